// Round 8
// baseline (2067.229 us; speedup 1.0000x reference)
//
#include <hip/hip_runtime.h>

// Problem constants
#define BATCH 4
#define SEQ   2048
#define HIDC  2048
#define NHC   16
#define DKC   128
#define DVC   128
#define MROWS (BATCH * SEQ)   // 8192
#define NDC   2048            // NH*DK = NH*DV

typedef __bf16 bf16_t;
typedef __bf16 bf16x8 __attribute__((ext_vector_type(8)));
typedef __bf16 bf16x2 __attribute__((ext_vector_type(2)));
typedef float  floatx4 __attribute__((ext_vector_type(4)));
typedef float  floatx2 __attribute__((ext_vector_type(2)));

__device__ __forceinline__ float sigf(float z) { return 1.f / (1.f + __expf(-z)); }

// async global->LDS, 16B per lane. LDS dest is wave-uniform base + lane*16.
#define GLL16(g, l)                                                              \
  __builtin_amdgcn_global_load_lds(                                              \
      (const __attribute__((address_space(1))) void*)(g),                        \
      (__attribute__((address_space(3))) void*)(l), 16, 0, 0)

// 16-lane sum reduce, entirely on the VALU pipe (DPP, no LDS).
__device__ __forceinline__ float red16(float x) {
  int a;
  a = __float_as_int(x);
  x += __int_as_float(__builtin_amdgcn_update_dpp(a, a, 0xB1, 0xF, 0xF, true));   // xor 1
  a = __float_as_int(x);
  x += __int_as_float(__builtin_amdgcn_update_dpp(a, a, 0x4E, 0xF, 0xF, true));   // xor 2
  a = __float_as_int(x);
  x += __int_as_float(__builtin_amdgcn_update_dpp(a, a, 0x141, 0xF, 0xF, true));  // row_half_mirror
  a = __float_as_int(x);
  x += __int_as_float(__builtin_amdgcn_update_dpp(a, a, 0x140, 0xF, 0xF, true));  // row_mirror
  return x;
}

// packed-fp32 dot over 8 elems held as 4x float2 (v_pk_fma_f32 path).
__device__ __forceinline__ float dot8p(const floatx2* a, const floatx2* b) {
  floatx2 d0 = a[0] * b[0];
  floatx2 d1 = a[1] * b[1];
  d0 = a[2] * b[2] + d0;
  d1 = a[3] * b[3] + d1;
  floatx2 d = d0 + d1;
  return d[0] + d[1];
}

// load 8 floats into 4x float2
#define LD8V(dst, ptr)                               \
  {                                                  \
    *(float4*)&dst[0] = ((const float4*)(ptr))[0];   \
    *(float4*)&dst[2] = ((const float4*)(ptr))[1];   \
  }

// ---------------------------------------------------------------------------
// fp32 -> bf16 convert (8 elems/thread)
// ---------------------------------------------------------------------------
__global__ __launch_bounds__(256) void f2b_k(const float* __restrict__ src,
                                             bf16_t* __restrict__ dst) {
  size_t i = ((size_t)blockIdx.x * 256 + threadIdx.x) * 8;
  float4 a = *(const float4*)(src + i);
  float4 b = *(const float4*)(src + i + 4);
  bf16_t tmp[8] = {(bf16_t)a.x, (bf16_t)a.y, (bf16_t)a.z, (bf16_t)a.w,
                   (bf16_t)b.x, (bf16_t)b.y, (bf16_t)b.z, (bf16_t)b.w};
  *(bf16x8*)(dst + i) = *(bf16x8*)tmp;
}

// ---------------------------------------------------------------------------
// Transpose+convert 2048x2048: Wt[n][k] = bf16(W[k][n]), W fp32
// ---------------------------------------------------------------------------
__global__ __launch_bounds__(256) void transpose_k(const float* __restrict__ W,
                                                   bf16_t* __restrict__ Wt) {
  __shared__ float tile[32][33];
  int kb = blockIdx.x * 32, nb = blockIdx.y * 32;
  int tx = threadIdx.x, ty = threadIdx.y;  // (32,8)
#pragma unroll
  for (int r = 0; r < 4; ++r)
    tile[ty + 8 * r][tx] = W[(size_t)(kb + ty + 8 * r) * 2048 + nb + tx];
  __syncthreads();
#pragma unroll
  for (int r = 0; r < 4; ++r)
    Wt[(size_t)(nb + ty + 8 * r) * 2048 + kb + tx] = (bf16_t)tile[tx][ty + 8 * r];
}

// ---------------------------------------------------------------------------
// Transpose Wb 2048x16 -> Wbt 16x2048 (fp32), one-time 128KB shuffle.
// ---------------------------------------------------------------------------
__global__ __launch_bounds__(256) void wbt_k(const float* __restrict__ Wb,
                                             float* __restrict__ Wbt) {
  int idx = blockIdx.x * 256 + threadIdx.x;  // < 16*2048
  int n = idx >> 11;
  int j = idx & 2047;
  Wbt[idx] = Wb[(size_t)j * NHC + n];
}

// ---------------------------------------------------------------------------
// 2-PHASE double-buffered bf16 MFMA GEMM (NT): 128x128 tile, BK=32, 4 waves.
// Measured 207us / 830 TF for the fused proj dispatch - at the m97-structure
// ceiling (LDS-read-bound). FLAT 1-D grid + XCD-chunked swizzle.
// MODE 0: fused 5-segment projection GEMM (stacked B, segment = ncol>>4).
// MODE 1: output GEMM (C rows chunk-mapped), 16 columns.
// ---------------------------------------------------------------------------
template <int MODE>
__global__ __launch_bounds__(256) void gemm97(const bf16_t* __restrict__ A,
                                              const bf16_t* __restrict__ Bt,
                                              float* __restrict__ C0,
                                              float* __restrict__ C1,
                                              float* __restrict__ C2,
                                              float* __restrict__ C3,
                                              float* __restrict__ C4,
                                              const float* __restrict__ bias,
                                              int cOff, int scShift,
                                              int mbLog, int swz) {
  __shared__ bf16_t As[2 * 128 * 32];
  __shared__ bf16_t Bs[2 * 128 * 32];
  const int tid = threadIdx.x;
  const int wave = tid >> 6;
  const int lane = tid & 63;
  const int f = blockIdx.x;
  int mblk, ncol;
  if (swz) {
    const int xcd = f & 7;
    const int slot = f >> 3;
    const int mper = mbLog - 3;                      // log2(m-blocks per XCD)
    mblk = (xcd << mper) + (slot & ((1 << mper) - 1));
    ncol = slot >> mper;
  } else {
    mblk = f & ((1 << mbLog) - 1);
    ncol = f >> mbLog;
  }
  const int m0 = mblk * 128;
  const int n0 = ncol * 128;
  const int K = 2048;
  const int scMask = (1 << scShift) - 1;
  const int ga = (MODE == 0) ? (((m0 >> scShift) << 11) + cOff + (m0 & scMask)) : m0;
  const int gc = (MODE == 1) ? (((m0 >> scShift) << 11) + cOff + (m0 & scMask)) : m0;

  const int wm = (wave >> 1) * 64;
  const int wn = (wave & 1) * 64;
  const int qd = lane >> 4;   // quad 0..3
  const int l16 = lane & 15;

  // staging geometry: wave w covers rows {16w..16w+15} and {64+16w..}
  const int srow = lane >> 2;          // 0..15 row-within-chunk
  const int skel = (lane & 3) * 8;     // element offset within 32-elem row

  const bf16_t* agA0 = A + (size_t)(ga + 16 * wave + srow) * K + skel;
  const bf16_t* agA1 = agA0 + (size_t)64 * K;
  const bf16_t* bgB0 = Bt + (size_t)(n0 + 16 * wave + srow) * K + skel;
  const bf16_t* bgB1 = bgB0 + (size_t)64 * K;
  bf16_t* lA0 = &As[(16 * wave) * 32];
  bf16_t* lA1 = &As[(64 + 16 * wave) * 32];
  bf16_t* lB0 = &Bs[(16 * wave) * 32];
  bf16_t* lB1 = &Bs[(64 + 16 * wave) * 32];

  const bf16_t* pa[4];
  const bf16_t* pb[4];
#pragma unroll
  for (int i = 0; i < 4; ++i) {
    pa[i] = &As[(wm + 16 * i + l16) * 32 + qd * 8];
    pb[i] = &Bs[(wn + 16 * i + l16) * 32 + qd * 8];
  }

  const floatx4 fzero = {0.f, 0.f, 0.f, 0.f};
  floatx4 acc[4][4];
#pragma unroll
  for (int i = 0; i < 4; ++i)
#pragma unroll
    for (int j = 0; j < 4; ++j) acc[i][j] = fzero;

  auto stage = [&](int B, int KO) {
    const int off = B * 4096;  // 128*32 elems per buffer
    GLL16(agA0 + KO, lA0 + off);
    GLL16(agA1 + KO, lA1 + off);
    GLL16(bgB0 + KO, lB0 + off);
    GLL16(bgB1 + KO, lB1 + off);
  };
  auto compute = [&](int B) {
    const int off = B * 4096;
    bf16x8 afr[4], bfr[4];
#pragma unroll
    for (int i = 0; i < 4; ++i) afr[i] = *(const bf16x8*)(pa[i] + off);
#pragma unroll
    for (int j = 0; j < 4; ++j) bfr[j] = *(const bf16x8*)(pb[j] + off);
#pragma unroll
    for (int i = 0; i < 4; ++i)
#pragma unroll
      for (int j = 0; j < 4; ++j)
        acc[i][j] = __builtin_amdgcn_mfma_f32_16x16x32_bf16(afr[i], bfr[j], acc[i][j], 0, 0, 0);
  };

  // prologue: fill buf0 with tile 0
  stage(0, 0);
  __syncthreads();
  int k0 = 0;
  for (; k0 < K - 64; k0 += 64) {
    stage(1, k0 + 32);   // issue next tile BEFORE computing current
    compute(0);          // tile k0 from buf0
    __syncthreads();     // vmcnt(0): buf1 staged; lgkm: buf0 reads done
    stage(0, k0 + 64);
    compute(1);          // tile k0+32 from buf1
    __syncthreads();
  }
  // tail: k0 == K-64
  stage(1, k0 + 32);
  compute(0);
  __syncthreads();
  compute(1);

  // C/D layout: col(N) = lane&15, row(M) = (lane>>4)*4 + reg  [measured m89]
  if (MODE == 0) {
    const int sid = ncol >> 4;
    float* Cp = (sid == 0) ? C0 : (sid == 1) ? C1 : (sid == 2) ? C2 : (sid == 3) ? C3 : C4;
    const int nb = (ncol & 15) * 128;
#pragma unroll
    for (int i = 0; i < 4; ++i)
#pragma unroll
      for (int j = 0; j < 4; ++j)
#pragma unroll
        for (int r = 0; r < 4; ++r) {
          int mm = m0 + wm + 16 * i + qd * 4 + r;
          int nn = nb + wn + 16 * j + l16;
          float val = acc[i][j][r];
          if (sid == 3) val = sigf(val + bias[nn]);
          else if (sid == 4) val = sigf(val);
          Cp[(size_t)mm * 2048 + nn] = val;
        }
  } else {
#pragma unroll
    for (int i = 0; i < 4; ++i)
#pragma unroll
      for (int j = 0; j < 4; ++j)
#pragma unroll
        for (int r = 0; r < 4; ++r) {
          int mm = gc + wm + 16 * i + qd * 4 + r;
          int nn = n0 + wn + 16 * j + l16;
          C0[(size_t)mm * 2048 + nn] = acc[i][j][r];
        }
  }
}

// ---------------------------------------------------------------------------
// beta = sigmoid(x @ Wb + bb)   NOW reads xb (bf16, half the traffic of fp32
// x; same precision as every other projection GEMM input). Wbt fp32 L2-hot.
// ---------------------------------------------------------------------------
__global__ __launch_bounds__(256) void beta_k(const bf16_t* __restrict__ xb,
                                              const float* __restrict__ Wbt,
                                              const float* __restrict__ bb,
                                              float* __restrict__ beta) {
  __shared__ float xs[4][HIDC];
  const int row0 = blockIdx.x * 4;
  for (int i = threadIdx.x; i < 4 * 256; i += 256) {  // 8 bf16 per iter
    int r = i >> 8;
    int j = i & 255;
    bf16x8 v = ((const bf16x8*)(xb + (size_t)(row0 + r) * HIDC))[j];
    float4 f0, f1;
#pragma unroll
    for (int e = 0; e < 4; ++e) {
      ((float*)&f0)[e] = (float)v[e];
      ((float*)&f1)[e] = (float)v[4 + e];
    }
    ((float4*)xs[r])[2 * j] = f0;
    ((float4*)xs[r])[2 * j + 1] = f1;
  }
  __syncthreads();
  const int wave = threadIdx.x >> 6, lane = threadIdx.x & 63;
#pragma unroll
  for (int nb = 0; nb < 4; ++nb) {
    const int n = wave + nb * 4;
    float acc0 = 0.f, acc1 = 0.f, acc2 = 0.f, acc3 = 0.f;
    const float4* wrow = (const float4*)(Wbt + (size_t)n * HIDC);
    for (int j = lane; j < HIDC / 4; j += 64) {
      float4 wv = wrow[j];
      float4 x0 = ((const float4*)xs[0])[j];
      float4 x1 = ((const float4*)xs[1])[j];
      float4 x2 = ((const float4*)xs[2])[j];
      float4 x3 = ((const float4*)xs[3])[j];
      acc0 += wv.x * x0.x + wv.y * x0.y + wv.z * x0.z + wv.w * x0.w;
      acc1 += wv.x * x1.x + wv.y * x1.y + wv.z * x1.z + wv.w * x1.w;
      acc2 += wv.x * x2.x + wv.y * x2.y + wv.z * x2.z + wv.w * x2.w;
      acc3 += wv.x * x3.x + wv.y * x3.y + wv.z * x3.z + wv.w * x3.w;
    }
    float accs[4] = {acc0, acc1, acc2, acc3};
#pragma unroll
    for (int r = 0; r < 4; ++r) {
      float s = accs[r];
#pragma unroll
      for (int off = 32; off; off >>= 1) s += __shfl_xor(s, off);
      if (lane == 0) beta[(size_t)(row0 + r) * NHC + n] = sigf(s + bb[n]);
    }
  }
}

// ---------------------------------------------------------------------------
// fused 3x causal depthwise conv (K=4) + bias + SiLU (*scale for k).
// VECTORIZED: float4 (4 channels) per thread - all loads/stores 16B (G13).
// Also writes next-chunk tails (pre-conv Y of last 3 rows/batch), ping-pong.
// ---------------------------------------------------------------------------
__global__ __launch_bounds__(256) void conv3_k(
    const float* __restrict__ Yq, const float* __restrict__ Yk,
    const float* __restrict__ Yv,
    const float* __restrict__ tqi, const float* __restrict__ tki,
    const float* __restrict__ tvi,
    float* __restrict__ tqo, float* __restrict__ tko,
    float* __restrict__ tvo,
    const float* __restrict__ cqw, const float* __restrict__ cqb,
    const float* __restrict__ ckw, const float* __restrict__ ckb,
    const float* __restrict__ cvw, const float* __restrict__ cvb,
    float* __restrict__ qb, float* __restrict__ kb,
    float* __restrict__ vb, int cOff, int scShift) {
  size_t idx = ((size_t)blockIdx.x * 256 + threadIdx.x) * 4;  // float index
  int ch = (int)(idx & 2047);
  int mloc = (int)(idx >> 11);
  int SCm = (1 << scShift);
  int sloc = mloc & (SCm - 1);
  int b = mloc >> scShift;
  int sg = cOff + sloc;
  float4 yq = *(const float4*)(Yq + idx);
  float4 yk = *(const float4*)(Yk + idx);
  float4 yv = *(const float4*)(Yv + idx);
  if (sloc >= SCm - 3) {  // stash pre-conv tail for next chunk
    int tt = sloc - (SCm - 3);
    size_t it = (size_t)(b * 3 + tt) * 2048 + ch;
    *(float4*)(tqo + it) = yq;
    *(float4*)(tko + it) = yk;
    *(float4*)(tvo + it) = yv;
  }
  float4 wq[4], wk[4], wv[4];
#pragma unroll
  for (int c = 0; c < 4; ++c) {
    wq[c] = *(const float4*)(cqw + (ch + c) * 4);  // .x=w0 .y=w1 .z=w2 .w=w3
    wk[c] = *(const float4*)(ckw + (ch + c) * 4);
    wv[c] = *(const float4*)(cvw + (ch + c) * 4);
  }
  float4 bq = *(const float4*)(cqb + ch);
  float4 bk = *(const float4*)(ckb + ch);
  float4 bv = *(const float4*)(cvb + ch);
  float aq[4], ak[4], av[4];
  {
    const float* yqa = (const float*)&yq;
    const float* yka = (const float*)&yk;
    const float* yva = (const float*)&yv;
    const float* bqa = (const float*)&bq;
    const float* bka = (const float*)&bk;
    const float* bva = (const float*)&bv;
#pragma unroll
    for (int c = 0; c < 4; ++c) {
      aq[c] = bqa[c] + wq[c].w * yqa[c];
      ak[c] = bka[c] + wk[c].w * yka[c];
      av[c] = bva[c] + wv[c].w * yva[c];
    }
  }
  if (sg >= 1) {
    bool in = sloc >= 1;
    size_t iy = idx - 2048;
    size_t it = (size_t)(b * 3 + 2 + sloc) * 2048 + ch;
    float4 pq = in ? *(const float4*)(Yq + iy) : *(const float4*)(tqi + it);
    float4 pk = in ? *(const float4*)(Yk + iy) : *(const float4*)(tki + it);
    float4 pv = in ? *(const float4*)(Yv + iy) : *(const float4*)(tvi + it);
    const float* pqa = (const float*)&pq;
    const float* pka = (const float*)&pk;
    const float* pva = (const float*)&pv;
#pragma unroll
    for (int c = 0; c < 4; ++c) {
      aq[c] += wq[c].z * pqa[c];
      ak[c] += wk[c].z * pka[c];
      av[c] += wv[c].z * pva[c];
    }
  }
  if (sg >= 2) {
    bool in = sloc >= 2;
    size_t iy = idx - 2 * 2048;
    size_t it = (size_t)(b * 3 + 1 + sloc) * 2048 + ch;
    float4 pq = in ? *(const float4*)(Yq + iy) : *(const float4*)(tqi + it);
    float4 pk = in ? *(const float4*)(Yk + iy) : *(const float4*)(tki + it);
    float4 pv = in ? *(const float4*)(Yv + iy) : *(const float4*)(tvi + it);
    const float* pqa = (const float*)&pq;
    const float* pka = (const float*)&pk;
    const float* pva = (const float*)&pv;
#pragma unroll
    for (int c = 0; c < 4; ++c) {
      aq[c] += wq[c].y * pqa[c];
      ak[c] += wk[c].y * pka[c];
      av[c] += wv[c].y * pva[c];
    }
  }
  if (sg >= 3) {
    bool in = sloc >= 3;
    size_t iy = idx - 3 * 2048;
    size_t it = (size_t)(b * 3 + sloc) * 2048 + ch;
    float4 pq = in ? *(const float4*)(Yq + iy) : *(const float4*)(tqi + it);
    float4 pk = in ? *(const float4*)(Yk + iy) : *(const float4*)(tki + it);
    float4 pv = in ? *(const float4*)(Yv + iy) : *(const float4*)(tvi + it);
    const float* pqa = (const float*)&pq;
    const float* pka = (const float*)&pk;
    const float* pva = (const float*)&pv;
#pragma unroll
    for (int c = 0; c < 4; ++c) {
      aq[c] += wq[c].x * pqa[c];
      ak[c] += wk[c].x * pka[c];
      av[c] += wv[c].x * pva[c];
    }
  }
  float4 oq, ok, ov;
  float* oqa = (float*)&oq;
  float* oka = (float*)&ok;
  float* ova = (float*)&ov;
#pragma unroll
  for (int c = 0; c < 4; ++c) {
    oqa[c] = aq[c] * sigf(aq[c]);
    oka[c] = ak[c] * sigf(ak[c]) * 0.08838834764831845f;
    ova[c] = av[c] * sigf(av[c]);
  }
  *(float4*)(qb + idx) = oq;
  *(float4*)(kb + idx) = ok;
  *(float4*)(vb + idx) = ov;
}

// ---------------------------------------------------------------------------
// delta-rule scan (chunked). Block = (b,h,16-row group); 512 blocks ->
// 2 blocks/CU (2 waves/SIMD). Thread owns 8 state elems as 4x float2; all
// FMA-side math packed fp32 (v_pk_fma_f32). Carried c via all-DPP red16.
// Unroll-4 ring buffers, prefetch distance 4. End-of-chunk overreads benign.
//   cf = beta*(c - v); St = a*St - cf*k; o = red(St.q); c' = red(St.k_next)
// ---------------------------------------------------------------------------
__global__ __launch_bounds__(256) void scan_k(const float* __restrict__ qf,
                                              const float* __restrict__ kf,
                                              const float* __restrict__ vf,
                                              const float* __restrict__ af,
                                              const float* __restrict__ betaf,
                                              float* __restrict__ of,
                                              float* __restrict__ state,
                                              int SC, int cOff, int init) {
  int blk = blockIdx.x;  // 0..511: (b<<7)|(h<<3)|rg
  int rg = blk & 7;
  int h = (blk >> 3) & 15;
  int b = blk >> 7;
  int t = threadIdx.x;
  int vrow = rg * 16 + (t >> 4);
  int l16 = t & 15;
  int e0 = l16 * 8;

  size_t stoff = ((size_t)((b * 16 + h) * 128 + vrow)) * 128 + e0;
  floatx2 St[4];
  if (init) {
#pragma unroll
    for (int i = 0; i < 4; ++i) { St[i][0] = 0.f; St[i][1] = 0.f; }
  } else {
    LD8V(St, state + stoff);
  }

  const size_t step = NDC;
  size_t base = (size_t)(b * SC) * step + (size_t)h * DKC;
  const float* qp = qf + base + e0;
  const float* kp = kf + base + e0;
  const float* vp = vf + base + vrow;
  const float* ap = af + base + vrow;
  const float* bp = betaf + ((size_t)b * SEQ + cOff) * NHC + h;
  float* op = of + base + vrow;

  floatx2 kr[4][4], qr[4][4];
  float vv[4], av[4], bv[4];
#pragma unroll
  for (int j = 0; j < 4; ++j) {
    LD8V(kr[j], kp + (size_t)j * step);
    LD8V(qr[j], qp + (size_t)j * step);
    vv[j] = vp[j * step];
    av[j] = ap[j * step];
    bv[j] = bp[j * NHC];
  }
  float c = red16(dot8p(St, kr[0]));

  for (int s = 0; s < SC; s += 4) {
#pragma unroll
    for (int j = 0; j < 4; ++j) {
      float cf = bv[j] * (c - vv[j]);
      float at = av[j];
      floatx2 at2; at2[0] = at; at2[1] = at;
      floatx2 cf2; cf2[0] = cf; cf2[1] = cf;
#pragma unroll
      for (int i = 0; i < 4; ++i) St[i] = at2 * St[i] - cf2 * kr[j][i];
      float ov = red16(dot8p(St, qr[j]));
      if (l16 == 0) op[(size_t)j * step] = ov;
      // refill slot j with step s+4+j (prefetch distance 4)
      LD8V(kr[j], kp + (size_t)(j + 4) * step);
      LD8V(qr[j], qp + (size_t)(j + 4) * step);
      vv[j] = vp[(j + 4) * step];
      av[j] = ap[(j + 4) * step];
      bv[j] = bp[(j + 4) * NHC];
      // carried dot for step s+j+1: slot (j+1)&3 still holds k[s+j+1] for
      // j<3; for j==3, kr[0] was refilled with k[s+4] three sub-steps ago.
      c = red16(dot8p(St, kr[(j + 1) & 3]));
    }
    qp += 4 * step; kp += 4 * step; vp += 4 * step; ap += 4 * step;
    bp += 4 * NHC; op += 4 * step;
  }

  ((float4*)(state + stoff))[0] = *(float4*)&St[0];
  ((float4*)(state + stoff))[1] = *(float4*)&St[2];
}

// ---------------------------------------------------------------------------
// per-(row,head) LayerNorm over DV=128 + ln affine + sigmoid-gate, write bf16
// VECTORIZED: float2 loads, bf16x2 store, ln affine hoisted out of h-loop.
// ---------------------------------------------------------------------------
__global__ __launch_bounds__(256) void ln_gate_k(const float* __restrict__ o,
                                                 const float* __restrict__ g,
                                                 const float* __restrict__ lnw,
                                                 const float* __restrict__ lnb,
                                                 bf16_t* __restrict__ ofin) {
  int row = blockIdx.x;
  int wave = threadIdx.x >> 6, lane = threadIdx.x & 63;
  float2 lw = *(const float2*)(lnw + 2 * lane);
  float2 lb = *(const float2*)(lnb + 2 * lane);
  for (int h = wave; h < NHC; h += 4) {
    size_t off = (size_t)row * 2048 + (size_t)h * DVC + 2 * lane;
    float2 xv = *(const float2*)(o + off);
    float2 gv = *(const float2*)(g + off);
    float s1 = xv.x + xv.y, s2 = xv.x * xv.x + xv.y * xv.y;
#pragma unroll
    for (int sh = 32; sh; sh >>= 1) {
      s1 += __shfl_xor(s1, sh);
      s2 += __shfl_xor(s2, sh);
    }
    float mu = s1 * (1.f / 128.f);
    float var = s2 * (1.f / 128.f) - mu * mu;
    float inv = rsqrtf(fmaxf(var, 0.f) + 1e-5f);
    bf16x2 outv;
    outv[0] = (bf16_t)(((xv.x - mu) * inv * lw.x + lb.x) * gv.x);
    outv[1] = (bf16_t)(((xv.y - mu) * inv * lw.y + lb.y) * gv.y);
    *(bf16x2*)(ofin + off) = outv;
  }
}

// ---------------------------------------------------------------------------
extern "C" void kernel_launch(void* const* d_in, const int* in_sizes, int n_in,
                              void* d_out, int out_size, void* d_ws, size_t ws_size,
                              hipStream_t stream) {
  const float* x   = (const float*)d_in[0];
  const float* Wq  = (const float*)d_in[1];
  const float* Wk  = (const float*)d_in[2];
  const float* Wv  = (const float*)d_in[3];
  const float* Wa  = (const float*)d_in[4];
  const float* ba  = (const float*)d_in[5];
  const float* Wb  = (const float*)d_in[6];
  const float* bb  = (const float*)d_in[7];
  const float* Wg  = (const float*)d_in[8];
  const float* Wo  = (const float*)d_in[9];
  const float* cqw = (const float*)d_in[10];
  const float* cqb = (const float*)d_in[11];
  const float* ckw = (const float*)d_in[12];
  const float* ckb = (const float*)d_in[13];
  const float* cvw = (const float*)d_in[14];
  const float* cvb = (const float*)d_in[15];
  const float* lnw = (const float*)d_in[16];
  const float* lnb = (const float*)d_in[17];
  float* outp = (float*)d_out;

  // --- pick chunking so the workspace fits ws_size ---
  const size_t WT    = (size_t)2048 * 2048 * sizeof(bf16_t);       // 8MB
  const size_t XB    = (size_t)MROWS * 2048 * sizeof(bf16_t);      // 32MB
  const size_t STATE = (size_t)4 * 16 * 128 * 128 * sizeof(float); // 4MB
  const size_t BETA  = (size_t)MROWS * NHC * sizeof(float);        // 512KB
  const size_t TAIL  = (size_t)4 * 3 * 2048 * sizeof(float);       // 96KB
  const size_t WBT   = (size_t)NHC * 2048 * sizeof(float);         // 128KB
  int nc = 16;
  {
    const int cands[5] = {1, 2, 4, 8, 16};
    for (int ci = 0; ci < 5; ++ci) {
      size_t CHc = ((size_t)MROWS / cands[ci]) * 2048 * sizeof(float);
      size_t need = 6 * WT + XB + 8 * CHc + STATE + BETA + 6 * TAIL + WBT + 4096;
      if (need <= ws_size) { nc = cands[ci]; break; }
    }
  }
  const int SC = SEQ / nc;
  int scShift = 0;
  while ((1 << scShift) < SC) ++scShift;
  const int Mc = MROWS / nc;  // chunk-local rows
  const size_t CH = (size_t)Mc * 2048 * sizeof(float);

  const int MB = Mc / 128;    // m-blocks per GEMM dispatch (power of 2)
  int mbLog = 0;
  while ((1 << mbLog) < MB) ++mbLog;
  const int swz = (MB >= 8) ? 1 : 0;  // XCD-chunked swizzle needs >=8 stripes

  // --- workspace layout (Wtq..Wtg MUST stay contiguous: stacked-B GEMM) ---
  char* w = (char*)d_ws;
  bf16_t* Wtq = (bf16_t*)w; w += WT;
  bf16_t* Wtk = (bf16_t*)w; w += WT;
  bf16_t* Wtv = (bf16_t*)w; w += WT;
  bf16_t* Wta = (bf16_t*)w; w += WT;
  bf16_t* Wtg = (bf16_t*)w; w += WT;
  bf16_t* Wto = (bf16_t*)w; w += WT;
  bf16_t* xb  = (bf16_t*)w; w += XB;
  float* Yq = (float*)w; w += CH;
  float* Yk = (float*)w; w += CH;
  float* Yv = (float*)w; w += CH;
  float* Za = (float*)w; w += CH;   // sigmoid fused in GEMM epilogue -> a
  float* Zg = (float*)w; w += CH;   // sigmoid fused in GEMM epilogue -> g
  float* qb = (float*)w; w += CH;
  float* kb = (float*)w; w += CH;
  float* vb = (float*)w; w += CH;
  float* betab = (float*)w; w += BETA;
  float* state = (float*)w; w += STATE;
  float* tails[2][3];
  for (int p = 0; p < 2; ++p)
    for (int q = 0; q < 3; ++q) { tails[p][q] = (float*)w; w += TAIL; }
  float* Wbt = (float*)w; w += WBT;
  float* ob = Yq;              // alias: Yq dead after conv of this chunk
  bf16_t* ofin = (bf16_t*)Yk;  // alias: Yk dead after conv of this chunk

  dim3 tb(32, 8);
  dim3 tg(64, 64);
  transpose_k<<<tg, tb, 0, stream>>>(Wq, Wtq);
  transpose_k<<<tg, tb, 0, stream>>>(Wk, Wtk);
  transpose_k<<<tg, tb, 0, stream>>>(Wv, Wtv);
  transpose_k<<<tg, tb, 0, stream>>>(Wa, Wta);
  transpose_k<<<tg, tb, 0, stream>>>(Wg, Wtg);
  transpose_k<<<tg, tb, 0, stream>>>(Wo, Wto);
  f2b_k<<<MROWS * 2048 / (256 * 8), 256, 0, stream>>>(x, xb);
  wbt_k<<<(NHC * 2048) / 256, 256, 0, stream>>>(Wb, Wbt);

  beta_k<<<MROWS / 4, 256, 0, stream>>>(xb, Wbt, bb, betab);

  const int gg5 = MB * 80;  // fused q,k,v,a,g projections (stacked B), flat
  const int ggo = MB * 16;  // output GEMM, flat
  const int eblocks = (int)(((size_t)Mc * 2048) / (256 * 4));

  for (int c = 0; c < nc; ++c) {
    const int cOff = c * SC;
    const int pi = c & 1, po = pi ^ 1;
    gemm97<0><<<gg5, 256, 0, stream>>>(xb, Wtq, Yq, Yk, Yv, Za, Zg, ba, cOff, scShift,
                                       mbLog, swz);

    conv3_k<<<eblocks, 256, 0, stream>>>(Yq, Yk, Yv,
                                         tails[pi][0], tails[pi][1], tails[pi][2],
                                         tails[po][0], tails[po][1], tails[po][2],
                                         cqw, cqb, ckw, ckb, cvw, cvb,
                                         qb, kb, vb, cOff, scShift);

    scan_k<<<512, 256, 0, stream>>>(qb, kb, vb, Za, betab, ob, state, SC, cOff, c == 0 ? 1 : 0);

    ln_gate_k<<<Mc, 256, 0, stream>>>(ob, Zg, lnw, lnb, ofin);

    gemm97<1><<<ggo, 256, 0, stream>>>(ofin, Wto, outp, nullptr, nullptr, nullptr, nullptr,
                                       nullptr, cOff, scShift, mbLog, swz);
  }
}

// Round 9
// 1587.653 us; speedup vs baseline: 1.3021x; 1.3021x over previous
//
#include <hip/hip_runtime.h>

// Problem constants
#define BATCH 4
#define SEQ   2048
#define HIDC  2048
#define NHC   16
#define DKC   128
#define DVC   128
#define MROWS (BATCH * SEQ)   // 8192
#define NDC   2048            // NH*DK = NH*DV

typedef __bf16 bf16_t;
typedef __bf16 bf16x8 __attribute__((ext_vector_type(8)));
typedef __bf16 bf16x2 __attribute__((ext_vector_type(2)));
typedef float  floatx4 __attribute__((ext_vector_type(4)));
typedef float  floatx2 __attribute__((ext_vector_type(2)));

__device__ __forceinline__ float sigf(float z) { return 1.f / (1.f + __expf(-z)); }

// async global->LDS, 16B per lane. LDS dest is wave-uniform base + lane*16.
#define GLL16(g, l)                                                              \
  __builtin_amdgcn_global_load_lds(                                              \
      (const __attribute__((address_space(1))) void*)(g),                        \
      (__attribute__((address_space(3))) void*)(l), 16, 0, 0)

// 16-lane sum reduce, entirely on the VALU pipe (DPP, no LDS).
__device__ __forceinline__ float red16(float x) {
  int a;
  a = __float_as_int(x);
  x += __int_as_float(__builtin_amdgcn_update_dpp(a, a, 0xB1, 0xF, 0xF, true));   // xor 1
  a = __float_as_int(x);
  x += __int_as_float(__builtin_amdgcn_update_dpp(a, a, 0x4E, 0xF, 0xF, true));   // xor 2
  a = __float_as_int(x);
  x += __int_as_float(__builtin_amdgcn_update_dpp(a, a, 0x141, 0xF, 0xF, true));  // row_half_mirror
  a = __float_as_int(x);
  x += __int_as_float(__builtin_amdgcn_update_dpp(a, a, 0x140, 0xF, 0xF, true));  // row_mirror
  return x;
}

// packed-fp32 dot over 8 elems held as 4x float2 (v_pk_fma_f32 path).
__device__ __forceinline__ float dot8p(const floatx2* a, const floatx2* b) {
  floatx2 d0 = a[0] * b[0];
  floatx2 d1 = a[1] * b[1];
  d0 = a[2] * b[2] + d0;
  d1 = a[3] * b[3] + d1;
  floatx2 d = d0 + d1;
  return d[0] + d[1];
}

// bf16x8 (4 dwords) -> 4x float2 in-register (shift/mask, 2 instr per pair)
__device__ __forceinline__ void b2f8(bf16x8 r, floatx2* d) {
  const int* w = (const int*)&r;
#pragma unroll
  for (int i = 0; i < 4; ++i) {
    int u = w[i];
    floatx2 t;
    t[0] = __int_as_float(u << 16);
    t[1] = __int_as_float(u & 0xffff0000);
    d[i] = t;
  }
}

// ---------------------------------------------------------------------------
// fp32 -> bf16 convert (8 elems/thread)
// ---------------------------------------------------------------------------
__global__ __launch_bounds__(256) void f2b_k(const float* __restrict__ src,
                                             bf16_t* __restrict__ dst) {
  size_t i = ((size_t)blockIdx.x * 256 + threadIdx.x) * 8;
  float4 a = *(const float4*)(src + i);
  float4 b = *(const float4*)(src + i + 4);
  bf16_t tmp[8] = {(bf16_t)a.x, (bf16_t)a.y, (bf16_t)a.z, (bf16_t)a.w,
                   (bf16_t)b.x, (bf16_t)b.y, (bf16_t)b.z, (bf16_t)b.w};
  *(bf16x8*)(dst + i) = *(bf16x8*)tmp;
}

// ---------------------------------------------------------------------------
// Transpose+convert 2048x2048: Wt[n][k] = bf16(W[k][n]), W fp32
// ---------------------------------------------------------------------------
__global__ __launch_bounds__(256) void transpose_k(const float* __restrict__ W,
                                                   bf16_t* __restrict__ Wt) {
  __shared__ float tile[32][33];
  int kb = blockIdx.x * 32, nb = blockIdx.y * 32;
  int tx = threadIdx.x, ty = threadIdx.y;  // (32,8)
#pragma unroll
  for (int r = 0; r < 4; ++r)
    tile[ty + 8 * r][tx] = W[(size_t)(kb + ty + 8 * r) * 2048 + nb + tx];
  __syncthreads();
#pragma unroll
  for (int r = 0; r < 4; ++r)
    Wt[(size_t)(nb + ty + 8 * r) * 2048 + kb + tx] = (bf16_t)tile[tx][ty + 8 * r];
}

// ---------------------------------------------------------------------------
// Transpose Wb 2048x16 -> Wbt 16x2048 (fp32), one-time 128KB shuffle.
// ---------------------------------------------------------------------------
__global__ __launch_bounds__(256) void wbt_k(const float* __restrict__ Wb,
                                             float* __restrict__ Wbt) {
  int idx = blockIdx.x * 256 + threadIdx.x;  // < 16*2048
  int n = idx >> 11;
  int j = idx & 2047;
  Wbt[idx] = Wb[(size_t)j * NHC + n];
}

// ---------------------------------------------------------------------------
// Transpose conv weights [2048][1][4] -> cwT[3 streams][4 taps][2048] fp32.
// ---------------------------------------------------------------------------
__global__ __launch_bounds__(256) void cwt_k(const float* __restrict__ cqw,
                                             const float* __restrict__ ckw,
                                             const float* __restrict__ cvw,
                                             float* __restrict__ cwT) {
  int idx = blockIdx.x * 256 + threadIdx.x;  // < 3*4*2048
  int c = idx & 2047;
  int t = (idx >> 11) & 3;
  int s = idx >> 13;
  const float* w = (s == 0) ? cqw : (s == 1) ? ckw : cvw;
  cwT[idx] = w[c * 4 + t];
}

// ---------------------------------------------------------------------------
// 2-PHASE double-buffered bf16 MFMA GEMM (NT): 128x128 tile, BK=32, 4 waves.
// FLAT 1-D grid + XCD-chunked swizzle.
// MODE 0: fused 5-segment projection GEMM (stacked B, segment = ncol>>4).
//         Outputs: sid 0,1,2 -> bf16 (Yq/Yk/Yv); sid 3 -> fp32 sig+bias (Za);
//         sid 4 -> fp32 sig (Zg).
// MODE 1: output GEMM (C rows chunk-mapped), C0 = fp32 out.
// ---------------------------------------------------------------------------
template <int MODE>
__global__ __launch_bounds__(256) void gemm97(const bf16_t* __restrict__ A,
                                              const bf16_t* __restrict__ Bt,
                                              void* __restrict__ C0,
                                              void* __restrict__ C1,
                                              void* __restrict__ C2,
                                              void* __restrict__ C3,
                                              void* __restrict__ C4,
                                              const float* __restrict__ bias,
                                              int cOff, int scShift,
                                              int mbLog, int swz) {
  __shared__ bf16_t As[2 * 128 * 32];
  __shared__ bf16_t Bs[2 * 128 * 32];
  const int tid = threadIdx.x;
  const int wave = tid >> 6;
  const int lane = tid & 63;
  const int f = blockIdx.x;
  int mblk, ncol;
  if (swz) {
    const int xcd = f & 7;
    const int slot = f >> 3;
    const int mper = mbLog - 3;                      // log2(m-blocks per XCD)
    mblk = (xcd << mper) + (slot & ((1 << mper) - 1));
    ncol = slot >> mper;
  } else {
    mblk = f & ((1 << mbLog) - 1);
    ncol = f >> mbLog;
  }
  const int m0 = mblk * 128;
  const int n0 = ncol * 128;
  const int K = 2048;
  const int scMask = (1 << scShift) - 1;
  const int ga = (MODE == 0) ? (((m0 >> scShift) << 11) + cOff + (m0 & scMask)) : m0;
  const int gc = (MODE == 1) ? (((m0 >> scShift) << 11) + cOff + (m0 & scMask)) : m0;

  const int wm = (wave >> 1) * 64;
  const int wn = (wave & 1) * 64;
  const int qd = lane >> 4;   // quad 0..3
  const int l16 = lane & 15;

  const int srow = lane >> 2;          // 0..15 row-within-chunk
  const int skel = (lane & 3) * 8;     // element offset within 32-elem row

  const bf16_t* agA0 = A + (size_t)(ga + 16 * wave + srow) * K + skel;
  const bf16_t* agA1 = agA0 + (size_t)64 * K;
  const bf16_t* bgB0 = Bt + (size_t)(n0 + 16 * wave + srow) * K + skel;
  const bf16_t* bgB1 = bgB0 + (size_t)64 * K;
  bf16_t* lA0 = &As[(16 * wave) * 32];
  bf16_t* lA1 = &As[(64 + 16 * wave) * 32];
  bf16_t* lB0 = &Bs[(16 * wave) * 32];
  bf16_t* lB1 = &Bs[(64 + 16 * wave) * 32];

  const bf16_t* pa[4];
  const bf16_t* pb[4];
#pragma unroll
  for (int i = 0; i < 4; ++i) {
    pa[i] = &As[(wm + 16 * i + l16) * 32 + qd * 8];
    pb[i] = &Bs[(wn + 16 * i + l16) * 32 + qd * 8];
  }

  const floatx4 fzero = {0.f, 0.f, 0.f, 0.f};
  floatx4 acc[4][4];
#pragma unroll
  for (int i = 0; i < 4; ++i)
#pragma unroll
    for (int j = 0; j < 4; ++j) acc[i][j] = fzero;

  auto stage = [&](int B, int KO) {
    const int off = B * 4096;  // 128*32 elems per buffer
    GLL16(agA0 + KO, lA0 + off);
    GLL16(agA1 + KO, lA1 + off);
    GLL16(bgB0 + KO, lB0 + off);
    GLL16(bgB1 + KO, lB1 + off);
  };
  auto compute = [&](int B) {
    const int off = B * 4096;
    bf16x8 afr[4], bfr[4];
#pragma unroll
    for (int i = 0; i < 4; ++i) afr[i] = *(const bf16x8*)(pa[i] + off);
#pragma unroll
    for (int j = 0; j < 4; ++j) bfr[j] = *(const bf16x8*)(pb[j] + off);
#pragma unroll
    for (int i = 0; i < 4; ++i)
#pragma unroll
      for (int j = 0; j < 4; ++j)
        acc[i][j] = __builtin_amdgcn_mfma_f32_16x16x32_bf16(afr[i], bfr[j], acc[i][j], 0, 0, 0);
  };

  stage(0, 0);
  __syncthreads();
  int k0 = 0;
  for (; k0 < K - 64; k0 += 64) {
    stage(1, k0 + 32);
    compute(0);
    __syncthreads();
    stage(0, k0 + 64);
    compute(1);
    __syncthreads();
  }
  stage(1, k0 + 32);
  compute(0);
  __syncthreads();
  compute(1);

  // C/D layout: col(N) = lane&15, row(M) = (lane>>4)*4 + reg  [measured m89]
  if (MODE == 0) {
    const int sid = ncol >> 4;
    const int nb = (ncol & 15) * 128;
    if (sid == 3 || sid == 4) {
      float* Cp = (float*)((sid == 3) ? C3 : C4);
#pragma unroll
      for (int i = 0; i < 4; ++i)
#pragma unroll
        for (int j = 0; j < 4; ++j)
#pragma unroll
          for (int r = 0; r < 4; ++r) {
            int mm = m0 + wm + 16 * i + qd * 4 + r;
            int nn = nb + wn + 16 * j + l16;
            float val = acc[i][j][r];
            val = (sid == 3) ? sigf(val + bias[nn]) : sigf(val);
            Cp[(size_t)mm * 2048 + nn] = val;
          }
    } else {
      bf16_t* Cp = (bf16_t*)((sid == 0) ? C0 : (sid == 1) ? C1 : C2);
#pragma unroll
      for (int i = 0; i < 4; ++i)
#pragma unroll
        for (int j = 0; j < 4; ++j)
#pragma unroll
          for (int r = 0; r < 4; ++r) {
            int mm = m0 + wm + 16 * i + qd * 4 + r;
            int nn = nb + wn + 16 * j + l16;
            Cp[(size_t)mm * 2048 + nn] = (bf16_t)acc[i][j][r];
          }
    }
  } else {
    float* Cp = (float*)C0;
#pragma unroll
    for (int i = 0; i < 4; ++i)
#pragma unroll
      for (int j = 0; j < 4; ++j)
#pragma unroll
        for (int r = 0; r < 4; ++r) {
          int mm = gc + wm + 16 * i + qd * 4 + r;
          int nn = n0 + wn + 16 * j + l16;
          Cp[(size_t)mm * 2048 + nn] = acc[i][j][r];
        }
  }
}

// ---------------------------------------------------------------------------
// beta = sigmoid(x @ Wb + bb)   reads xb (bf16). Wbt fp32 L2-hot.
// ---------------------------------------------------------------------------
__global__ __launch_bounds__(256) void beta_k(const bf16_t* __restrict__ xb,
                                              const float* __restrict__ Wbt,
                                              const float* __restrict__ bb,
                                              float* __restrict__ beta) {
  __shared__ float xs[4][HIDC];
  const int row0 = blockIdx.x * 4;
  for (int i = threadIdx.x; i < 4 * 256; i += 256) {  // 8 bf16 per iter
    int r = i >> 8;
    int j = i & 255;
    bf16x8 v = ((const bf16x8*)(xb + (size_t)(row0 + r) * HIDC))[j];
    float4 f0, f1;
#pragma unroll
    for (int e = 0; e < 4; ++e) {
      ((float*)&f0)[e] = (float)v[e];
      ((float*)&f1)[e] = (float)v[4 + e];
    }
    ((float4*)xs[r])[2 * j] = f0;
    ((float4*)xs[r])[2 * j + 1] = f1;
  }
  __syncthreads();
  const int wave = threadIdx.x >> 6, lane = threadIdx.x & 63;
#pragma unroll
  for (int nb = 0; nb < 4; ++nb) {
    const int n = wave + nb * 4;
    float acc0 = 0.f, acc1 = 0.f, acc2 = 0.f, acc3 = 0.f;
    const float4* wrow = (const float4*)(Wbt + (size_t)n * HIDC);
    for (int j = lane; j < HIDC / 4; j += 64) {
      float4 wv = wrow[j];
      float4 x0 = ((const float4*)xs[0])[j];
      float4 x1 = ((const float4*)xs[1])[j];
      float4 x2 = ((const float4*)xs[2])[j];
      float4 x3 = ((const float4*)xs[3])[j];
      acc0 += wv.x * x0.x + wv.y * x0.y + wv.z * x0.z + wv.w * x0.w;
      acc1 += wv.x * x1.x + wv.y * x1.y + wv.z * x1.z + wv.w * x1.w;
      acc2 += wv.x * x2.x + wv.y * x2.y + wv.z * x2.z + wv.w * x2.w;
      acc3 += wv.x * x3.x + wv.y * x3.y + wv.z * x3.z + wv.w * x3.w;
    }
    float accs[4] = {acc0, acc1, acc2, acc3};
#pragma unroll
    for (int r = 0; r < 4; ++r) {
      float s = accs[r];
#pragma unroll
      for (int off = 32; off; off >>= 1) s += __shfl_xor(s, off);
      if (lane == 0) beta[(size_t)(row0 + r) * NHC + n] = sigf(s + bb[n]);
    }
  }
}

// ---------------------------------------------------------------------------
// fused 3x causal depthwise conv (K=4) + bias + SiLU (*scale for k).
// bf16 in / bf16 out, 8 channels per thread (16B loads/stores). Transposed
// weights cwT[stream][tap][2048] give contiguous float4 weight loads.
// Writes next-chunk pre-conv tails (ping-pong, bf16).
// ---------------------------------------------------------------------------
__global__ __launch_bounds__(256) void conv3_k(
    const bf16_t* __restrict__ Yq, const bf16_t* __restrict__ Yk,
    const bf16_t* __restrict__ Yv,
    const bf16_t* __restrict__ tqi, const bf16_t* __restrict__ tki,
    const bf16_t* __restrict__ tvi,
    bf16_t* __restrict__ tqo, bf16_t* __restrict__ tko,
    bf16_t* __restrict__ tvo,
    const float* __restrict__ cwT,
    const float* __restrict__ cqb, const float* __restrict__ ckb,
    const float* __restrict__ cvb,
    bf16_t* __restrict__ qb, bf16_t* __restrict__ kb,
    bf16_t* __restrict__ vb, int cOff, int scShift) {
  size_t idx = ((size_t)blockIdx.x * 256 + threadIdx.x) * 8;  // elem index
  int ch = (int)(idx & 2047);
  int mloc = (int)(idx >> 11);
  int SCm = (1 << scShift);
  int sloc = mloc & (SCm - 1);
  int b = mloc >> scShift;
  int sg = cOff + sloc;
  bool tout = (sloc >= SCm - 3);
  size_t itout = 0;
  if (tout) itout = (size_t)(b * 3 + (sloc - (SCm - 3))) * 2048 + ch;
  bool in1 = sloc >= 1, in2 = sloc >= 2, in3 = sloc >= 3;
  size_t it1 = (size_t)(b * 3 + 2 + sloc) * 2048 + ch;
  size_t it2 = (size_t)(b * 3 + 1 + sloc) * 2048 + ch;
  size_t it3 = (size_t)(b * 3 + sloc) * 2048 + ch;

  const bf16_t* Ys[3] = {Yq, Yk, Yv};
  const bf16_t* tis[3] = {tqi, tki, tvi};
  bf16_t* tos[3] = {tqo, tko, tvo};
  const float* bs[3] = {cqb, ckb, cvb};
  bf16_t* os[3] = {qb, kb, vb};
  const float scale[3] = {1.f, 0.08838834764831845f, 1.f};

#pragma unroll
  for (int s = 0; s < 3; ++s) {
    bf16x8 y = *(const bf16x8*)(Ys[s] + idx);
    if (tout) *(bf16x8*)(tos[s] + itout) = y;
    float a[8];
    {
      float4 b0 = *(const float4*)(bs[s] + ch);
      float4 b1 = *(const float4*)(bs[s] + ch + 4);
      float4 w0 = *(const float4*)(cwT + (s * 4 + 3) * 2048 + ch);
      float4 w1 = *(const float4*)(cwT + (s * 4 + 3) * 2048 + ch + 4);
#pragma unroll
      for (int e = 0; e < 4; ++e) {
        a[e] = ((const float*)&b0)[e] + ((const float*)&w0)[e] * (float)y[e];
        a[4 + e] = ((const float*)&b1)[e] + ((const float*)&w1)[e] * (float)y[4 + e];
      }
    }
    if (sg >= 1) {
      bf16x8 p = in1 ? *(const bf16x8*)(Ys[s] + idx - 2048)
                     : *(const bf16x8*)(tis[s] + it1);
      float4 w0 = *(const float4*)(cwT + (s * 4 + 2) * 2048 + ch);
      float4 w1 = *(const float4*)(cwT + (s * 4 + 2) * 2048 + ch + 4);
#pragma unroll
      for (int e = 0; e < 4; ++e) {
        a[e] += ((const float*)&w0)[e] * (float)p[e];
        a[4 + e] += ((const float*)&w1)[e] * (float)p[4 + e];
      }
    }
    if (sg >= 2) {
      bf16x8 p = in2 ? *(const bf16x8*)(Ys[s] + idx - 2 * 2048)
                     : *(const bf16x8*)(tis[s] + it2);
      float4 w0 = *(const float4*)(cwT + (s * 4 + 1) * 2048 + ch);
      float4 w1 = *(const float4*)(cwT + (s * 4 + 1) * 2048 + ch + 4);
#pragma unroll
      for (int e = 0; e < 4; ++e) {
        a[e] += ((const float*)&w0)[e] * (float)p[e];
        a[4 + e] += ((const float*)&w1)[e] * (float)p[4 + e];
      }
    }
    if (sg >= 3) {
      bf16x8 p = in3 ? *(const bf16x8*)(Ys[s] + idx - 3 * 2048)
                     : *(const bf16x8*)(tis[s] + it3);
      float4 w0 = *(const float4*)(cwT + (s * 4 + 0) * 2048 + ch);
      float4 w1 = *(const float4*)(cwT + (s * 4 + 0) * 2048 + ch + 4);
#pragma unroll
      for (int e = 0; e < 4; ++e) {
        a[e] += ((const float*)&w0)[e] * (float)p[e];
        a[4 + e] += ((const float*)&w1)[e] * (float)p[4 + e];
      }
    }
    bf16x8 o8;
#pragma unroll
    for (int e = 0; e < 8; ++e) {
      float t = a[e] * sigf(a[e]) * scale[s];
      o8[e] = (bf16_t)t;
    }
    *(bf16x8*)(os[s] + idx) = o8;
  }
}

// ---------------------------------------------------------------------------
// delta-rule scan (chunked). Block = (b,h,16-row group); 512 blocks ->
// 2 blocks/CU (2 waves/SIMD). Thread owns 8 state elems as 4x float2; packed
// fp32 math (v_pk_fma_f32). k/q/v inputs are bf16 (HALF the per-step load
// bytes of r8 - scan proven memory-stall-bound: r8 VALUBusy 39% at same
// duration as r2's 59%). Convert in-register (shift/mask, off-chain).
// State, a-gate, beta, output all stay fp32.
//   cf = beta*(c - v); St = a*St - cf*k; o = red(St.q); c' = red(St.k_next)
// ---------------------------------------------------------------------------
__global__ __launch_bounds__(256) void scan_k(const bf16_t* __restrict__ qf,
                                              const bf16_t* __restrict__ kf,
                                              const bf16_t* __restrict__ vf,
                                              const float* __restrict__ af,
                                              const float* __restrict__ betaf,
                                              float* __restrict__ of,
                                              float* __restrict__ state,
                                              int SC, int cOff, int init) {
  int blk = blockIdx.x;  // 0..511: (b<<7)|(h<<3)|rg
  int rg = blk & 7;
  int h = (blk >> 3) & 15;
  int b = blk >> 7;
  int t = threadIdx.x;
  int vrow = rg * 16 + (t >> 4);
  int l16 = t & 15;
  int e0 = l16 * 8;

  size_t stoff = ((size_t)((b * 16 + h) * 128 + vrow)) * 128 + e0;
  floatx2 St[4];
  if (init) {
#pragma unroll
    for (int i = 0; i < 4; ++i) { St[i][0] = 0.f; St[i][1] = 0.f; }
  } else {
    *(float4*)&St[0] = ((const float4*)(state + stoff))[0];
    *(float4*)&St[2] = ((const float4*)(state + stoff))[1];
  }

  const size_t step = NDC;
  size_t base = (size_t)(b * SC) * step + (size_t)h * DKC;
  const bf16_t* qp = qf + base + e0;
  const bf16_t* kp = kf + base + e0;
  const bf16_t* vp = vf + base + vrow;
  const float* ap = af + base + vrow;
  const float* bp = betaf + ((size_t)b * SEQ + cOff) * NHC + h;
  float* op = of + base + vrow;

  floatx2 kr[4][4], qr[4][4];
  float vv[4], av[4], bv[4];
#pragma unroll
  for (int j = 0; j < 4; ++j) {
    b2f8(*(const bf16x8*)(kp + (size_t)j * step), kr[j]);
    b2f8(*(const bf16x8*)(qp + (size_t)j * step), qr[j]);
    vv[j] = (float)vp[j * step];
    av[j] = ap[j * step];
    bv[j] = bp[j * NHC];
  }
  float c = red16(dot8p(St, kr[0]));

  for (int s = 0; s < SC; s += 4) {
#pragma unroll
    for (int j = 0; j < 4; ++j) {
      float cf = bv[j] * (c - vv[j]);
      float at = av[j];
      floatx2 at2; at2[0] = at; at2[1] = at;
      floatx2 cf2; cf2[0] = cf; cf2[1] = cf;
#pragma unroll
      for (int i = 0; i < 4; ++i) St[i] = at2 * St[i] - cf2 * kr[j][i];
      float ov = red16(dot8p(St, qr[j]));
      if (l16 == 0) op[(size_t)j * step] = ov;
      // refill slot j with step s+4+j (prefetch distance 4)
      b2f8(*(const bf16x8*)(kp + (size_t)(j + 4) * step), kr[j]);
      b2f8(*(const bf16x8*)(qp + (size_t)(j + 4) * step), qr[j]);
      vv[j] = (float)vp[(j + 4) * step];
      av[j] = ap[(j + 4) * step];
      bv[j] = bp[(j + 4) * NHC];
      // carried dot for step s+j+1: slot (j+1)&3 still holds k[s+j+1] for
      // j<3; for j==3, kr[0] was refilled with k[s+4] three sub-steps ago.
      c = red16(dot8p(St, kr[(j + 1) & 3]));
    }
    qp += 4 * step; kp += 4 * step; vp += 4 * step; ap += 4 * step;
    bp += 4 * NHC; op += 4 * step;
  }

  ((float4*)(state + stoff))[0] = *(float4*)&St[0];
  ((float4*)(state + stoff))[1] = *(float4*)&St[2];
}

// ---------------------------------------------------------------------------
// per-(row,head) LayerNorm over DV=128 + ln affine + sigmoid-gate, write bf16
// ---------------------------------------------------------------------------
__global__ __launch_bounds__(256) void ln_gate_k(const float* __restrict__ o,
                                                 const float* __restrict__ g,
                                                 const float* __restrict__ lnw,
                                                 const float* __restrict__ lnb,
                                                 bf16_t* __restrict__ ofin) {
  int row = blockIdx.x;
  int wave = threadIdx.x >> 6, lane = threadIdx.x & 63;
  float2 lw = *(const float2*)(lnw + 2 * lane);
  float2 lb = *(const float2*)(lnb + 2 * lane);
  for (int h = wave; h < NHC; h += 4) {
    size_t off = (size_t)row * 2048 + (size_t)h * DVC + 2 * lane;
    float2 xv = *(const float2*)(o + off);
    float2 gv = *(const float2*)(g + off);
    float s1 = xv.x + xv.y, s2 = xv.x * xv.x + xv.y * xv.y;
#pragma unroll
    for (int sh = 32; sh; sh >>= 1) {
      s1 += __shfl_xor(s1, sh);
      s2 += __shfl_xor(s2, sh);
    }
    float mu = s1 * (1.f / 128.f);
    float var = s2 * (1.f / 128.f) - mu * mu;
    float inv = rsqrtf(fmaxf(var, 0.f) + 1e-5f);
    bf16x2 outv;
    outv[0] = (bf16_t)(((xv.x - mu) * inv * lw.x + lb.x) * gv.x);
    outv[1] = (bf16_t)(((xv.y - mu) * inv * lw.y + lb.y) * gv.y);
    *(bf16x2*)(ofin + off) = outv;
  }
}

// ---------------------------------------------------------------------------
extern "C" void kernel_launch(void* const* d_in, const int* in_sizes, int n_in,
                              void* d_out, int out_size, void* d_ws, size_t ws_size,
                              hipStream_t stream) {
  const float* x   = (const float*)d_in[0];
  const float* Wq  = (const float*)d_in[1];
  const float* Wk  = (const float*)d_in[2];
  const float* Wv  = (const float*)d_in[3];
  const float* Wa  = (const float*)d_in[4];
  const float* ba  = (const float*)d_in[5];
  const float* Wb  = (const float*)d_in[6];
  const float* bb  = (const float*)d_in[7];
  const float* Wg  = (const float*)d_in[8];
  const float* Wo  = (const float*)d_in[9];
  const float* cqw = (const float*)d_in[10];
  const float* cqb = (const float*)d_in[11];
  const float* ckw = (const float*)d_in[12];
  const float* ckb = (const float*)d_in[13];
  const float* cvw = (const float*)d_in[14];
  const float* cvb = (const float*)d_in[15];
  const float* lnw = (const float*)d_in[16];
  const float* lnb = (const float*)d_in[17];
  float* outp = (float*)d_out;

  // --- pick chunking so the workspace fits ws_size ---
  const size_t WT    = (size_t)2048 * 2048 * sizeof(bf16_t);       // 8MB
  const size_t XB    = (size_t)MROWS * 2048 * sizeof(bf16_t);      // 32MB
  const size_t STATE = (size_t)4 * 16 * 128 * 128 * sizeof(float); // 4MB
  const size_t BETA  = (size_t)MROWS * NHC * sizeof(float);        // 512KB
  const size_t TAILB = (size_t)4 * 3 * 2048 * sizeof(bf16_t);      // 48KB
  const size_t WBT   = (size_t)NHC * 2048 * sizeof(float);         // 128KB
  const size_t CWT   = (size_t)3 * 4 * 2048 * sizeof(float);       // 96KB
  int nc = 16;
  {
    const int cands[5] = {1, 2, 4, 8, 16};
    for (int ci = 0; ci < 5; ++ci) {
      size_t CHb = ((size_t)MROWS / cands[ci]) * 2048 * sizeof(bf16_t);
      size_t CHf = 2 * CHb;
      size_t need = 6 * WT + XB + 6 * CHb + 2 * CHf + STATE + BETA + 6 * TAILB +
                    WBT + CWT + 4096;
      if (need <= ws_size) { nc = cands[ci]; break; }
    }
  }
  const int SC = SEQ / nc;
  int scShift = 0;
  while ((1 << scShift) < SC) ++scShift;
  const int Mc = MROWS / nc;  // chunk-local rows
  const size_t CHb = (size_t)Mc * 2048 * sizeof(bf16_t);
  const size_t CHf = 2 * CHb;

  const int MB = Mc / 128;    // m-blocks per GEMM dispatch (power of 2)
  int mbLog = 0;
  while ((1 << mbLog) < MB) ++mbLog;
  const int swz = (MB >= 8) ? 1 : 0;

  // --- workspace layout (Wtq..Wtg contiguous: stacked-B GEMM;
  //     Yq,Yk contiguous: fp32 ob alias spans both) ---
  char* w = (char*)d_ws;
  bf16_t* Wtq = (bf16_t*)w; w += WT;
  bf16_t* Wtk = (bf16_t*)w; w += WT;
  bf16_t* Wtv = (bf16_t*)w; w += WT;
  bf16_t* Wta = (bf16_t*)w; w += WT;
  bf16_t* Wtg = (bf16_t*)w; w += WT;
  bf16_t* Wto = (bf16_t*)w; w += WT;
  bf16_t* xb  = (bf16_t*)w; w += XB;
  bf16_t* Yq = (bf16_t*)w; w += CHb;
  bf16_t* Yk = (bf16_t*)w; w += CHb;
  bf16_t* Yv = (bf16_t*)w; w += CHb;
  float* Za = (float*)w; w += CHf;   // fp32: multiplicative gate, compounds
  float* Zg = (float*)w; w += CHf;   // fp32: output gate (cheap safety)
  bf16_t* qb = (bf16_t*)w; w += CHb;
  bf16_t* kb = (bf16_t*)w; w += CHb;
  bf16_t* vb = (bf16_t*)w; w += CHb;
  float* betab = (float*)w; w += BETA;
  float* state = (float*)w; w += STATE;
  bf16_t* tails[2][3];
  for (int p = 0; p < 2; ++p)
    for (int q = 0; q < 3; ++q) { tails[p][q] = (bf16_t*)w; w += TAILB; }
  float* Wbt = (float*)w; w += WBT;
  float* cwT = (float*)w; w += CWT;
  float* ob = (float*)Yq;      // alias: spans Yq+Yk (2*CHb = CHf); both dead
  bf16_t* ofin = Yv;           // alias: Yv dead after conv of this chunk

  dim3 tb(32, 8);
  dim3 tg(64, 64);
  transpose_k<<<tg, tb, 0, stream>>>(Wq, Wtq);
  transpose_k<<<tg, tb, 0, stream>>>(Wk, Wtk);
  transpose_k<<<tg, tb, 0, stream>>>(Wv, Wtv);
  transpose_k<<<tg, tb, 0, stream>>>(Wa, Wta);
  transpose_k<<<tg, tb, 0, stream>>>(Wg, Wtg);
  transpose_k<<<tg, tb, 0, stream>>>(Wo, Wto);
  f2b_k<<<MROWS * 2048 / (256 * 8), 256, 0, stream>>>(x, xb);
  wbt_k<<<(NHC * 2048) / 256, 256, 0, stream>>>(Wb, Wbt);
  cwt_k<<<(3 * 4 * 2048) / 256, 256, 0, stream>>>(cqw, ckw, cvw, cwT);

  beta_k<<<MROWS / 4, 256, 0, stream>>>(xb, Wbt, bb, betab);

  const int gg5 = MB * 80;  // fused q,k,v,a,g projections (stacked B), flat
  const int ggo = MB * 16;  // output GEMM, flat
  const int eblocks = (int)(((size_t)Mc * 2048) / (256 * 8));

  for (int c = 0; c < nc; ++c) {
    const int cOff = c * SC;
    const int pi = c & 1, po = pi ^ 1;
    gemm97<0><<<gg5, 256, 0, stream>>>(xb, Wtq, (void*)Yq, (void*)Yk, (void*)Yv,
                                       (void*)Za, (void*)Zg, ba, cOff, scShift,
                                       mbLog, swz);

    conv3_k<<<eblocks, 256, 0, stream>>>(Yq, Yk, Yv,
                                         tails[pi][0], tails[pi][1], tails[pi][2],
                                         tails[po][0], tails[po][1], tails[po][2],
                                         cwT, cqb, ckb, cvb,
                                         qb, kb, vb, cOff, scShift);

    scan_k<<<512, 256, 0, stream>>>(qb, kb, vb, Za, betab, ob, state, SC, cOff,
                                    c == 0 ? 1 : 0);

    ln_gate_k<<<Mc, 256, 0, stream>>>(ob, Zg, lnw, lnb, ofin);

    gemm97<1><<<ggo, 256, 0, stream>>>(ofin, Wto, (void*)outp, nullptr, nullptr,
                                       nullptr, nullptr, nullptr, cOff, scShift,
                                       mbLog, swz);
  }
}